// Round 7
// baseline (1734.034 us; speedup 1.0000x reference)
//
#include <hip/hip_runtime.h>
#include <math.h>

#define TT 512
#define DD 1024
#define BB 32
#define G3D (3*DD)
#define NBLK 256         // k_gru blocks: 4 batch-groups x 64 col-blocks
#define RG 8             // rows per batch group

typedef _Float16 f16;
typedef _Float16 f16x2 __attribute__((ext_vector_type(2)));
typedef _Float16 f16x4 __attribute__((ext_vector_type(4)));
typedef _Float16 f16x8 __attribute__((ext_vector_type(8)));
typedef float f32x2 __attribute__((ext_vector_type(2)));
typedef float f32x4 __attribute__((ext_vector_type(4)));
typedef unsigned long long u64;

// h exchange: [parity][group 0..3][colgroup 0..31][row 0..7][col 0..31] halves.
// Batch rows are INDEPENDENT GRU chains -> broadcast only within a group of
// 8 rows: each block reads 16KB/step (r6: 32KB, r5: 64KB). MFMA A-rows 8..15
// alias rows 0..7 (same address -> wave-coalesced, no extra line traffic);
// their output rows are never read.
// Per-(parity,group) slot = 32*8*32 halves = 16384 B. Total 128 KB.
// Protocol per group (PROVEN r2/r5/r6): publish 4B agent atomics -> counted
// vmcnt drain -> raw barrier -> per-block epoch flag + 64-way fan-in poll ->
// raw barrier. Tagged/flag-free variants were slower (r3/r4) - do not revisit.
// NEW r7: counted drain vmcnt(4) over asm-pinned [publish][gi x3][out] so the
// drain waits ONLY on the h-publish LLC ack; gi/out retire under the poll.
// (r6's __syncthreads lowered to vmcnt(0) -> drained the HBM out-store too.)
#define HSLOT_BYTES 16384

// ---------------------------------------------------------------- kernel A
__global__ void k_convert(const float* __restrict__ Wih, const float* __restrict__ Whh,
                          f16* __restrict__ Wih16, f16* __restrict__ Whh16,
                          u64* __restrict__ hX, unsigned int* __restrict__ flags) {
    int idx = blockIdx.x * 256 + threadIdx.x;
    int n = G3D * DD;
    if (idx < n) {
        Wih16[idx] = (f16)Wih[idx];
        Whh16[idx] = (f16)Whh[idx];
    }
    if (idx < 16384) hX[idx] = 0ull;          // all 8 slots zero (h0 = 0)
    if (idx < NBLK * 16) flags[idx] = 0u;     // 256 flags, 16-dword (64B) spacing
}

// ---------------------------------------------------------------- kernel B
// GI[16384][3072] = h_enc[16384][1024] * Wih^T + b_ih  (fp16 out)
#define BM 128
#define BN 128
#define BK 32
#define LDA 40

__global__ __launch_bounds__(256) void k_pregemm(
    const float* __restrict__ X,
    const f16*   __restrict__ W16,
    const float* __restrict__ bih,
    f16* __restrict__ GI)
{
    __shared__ f16 As[BM * LDA];
    __shared__ f16 Bs[BN * LDA];
    const int tid  = threadIdx.x;
    const int lane = tid & 63;
    const int wave = tid >> 6;
    const int wr = wave >> 1, wc = wave & 1;
    const int m0 = blockIdx.y * BM;
    const int n0 = blockIdx.x * BN;
    const int mfrag = lane & 15;
    const int qfrag = lane >> 4;

    f32x4 acc[4][4] = {};

    for (int kt = 0; kt < DD; kt += BK) {
        __syncthreads();
        {
            int row = tid >> 3;
            int c   = tid & 7;
            #pragma unroll
            for (int p = 0; p < 4; ++p) {
                int r = row + p * 32;
                float4 v = *(const float4*)(X + (size_t)(m0 + r) * DD + kt + c * 4);
                f16x4 hv = { (f16)v.x, (f16)v.y, (f16)v.z, (f16)v.w };
                *(f16x4*)(As + r * LDA + c * 4) = hv;
            }
        }
        {
            int row = tid >> 2;
            int c   = tid & 3;
            #pragma unroll
            for (int p = 0; p < 2; ++p) {
                int r = row + p * 64;
                f16x8 v = *(const f16x8*)(W16 + (size_t)(n0 + r) * DD + kt + c * 8);
                *(f16x8*)(Bs + r * LDA + c * 8) = v;
            }
        }
        __syncthreads();
        f16x8 af[4], bf[4];
        #pragma unroll
        for (int i = 0; i < 4; ++i)
            af[i] = *(const f16x8*)(As + (wr * 64 + i * 16 + mfrag) * LDA + qfrag * 8);
        #pragma unroll
        for (int j = 0; j < 4; ++j)
            bf[j] = *(const f16x8*)(Bs + (wc * 64 + j * 16 + mfrag) * LDA + qfrag * 8);
        #pragma unroll
        for (int i = 0; i < 4; ++i)
            #pragma unroll
            for (int j = 0; j < 4; ++j)
                acc[i][j] = __builtin_amdgcn_mfma_f32_16x16x32_f16(af[i], bf[j], acc[i][j], 0, 0, 0);
    }
    #pragma unroll
    for (int j = 0; j < 4; ++j) {
        int col = n0 + wc * 64 + j * 16 + mfrag;
        float bias = bih[col];
        #pragma unroll
        for (int i = 0; i < 4; ++i) {
            int rowb = m0 + wr * 64 + i * 16 + qfrag * 4;
            #pragma unroll
            for (int r = 0; r < 4; ++r)
                GI[(size_t)(rowb + r) * G3D + col] = (f16)(acc[i][j][r] + bias);
        }
    }
}

// ---------------------------------------------------------------- kernel C
// Persistent recurrent kernel: 256 blocks x 256 threads (4 waves = K-quarters).
// Block bid: group g = bid&3 (batch rows [8g,8g+8)), col-block cb = bid>>2
// (h columns [16cb,16cb+16)). Four groups run independent 64-block barriers.
// W_hh B-fragments in registers (96 VGPR, loop-invariant).
__global__ __launch_bounds__(256, 1) void k_gru(
    const f16* __restrict__ Whh16,   // [3072][1024]
    const f16* __restrict__ GI,      // [16384][3072]
    const float* __restrict__ bhh,   // [3072]
    float* __restrict__ out,         // [32][512][1024] fp32
    f16* __restrict__ hX,            // [2][4] blocked h slots
    unsigned int* __restrict__ flags)// [256] epoch flags, 16-dword spacing
{
    __shared__ float red[4][3][RG][21];     // 8064 B
    __shared__ float h32[RG][18];
    __shared__ float bh_s[3][16];

    const int tid  = threadIdx.x;
    const int lane = tid & 63;
    const int kq   = tid >> 6;        // wave id = K quarter (256)
    const int bid  = blockIdx.x;
    const int g    = bid & 3;         // batch group
    const int j0   = (bid >> 2) * 16; // owned h columns
    const int row0 = g * RG;          // owned batch rows
    const int mfrag = lane & 15;
    const int qk    = lane >> 4;      // 0..3

    // B-fragments -> registers, once. Lane (mfrag,qk) of wave kq holds
    // W_hh[gt*DD + j0 + mfrag][kq*256 + it*32 + qk*8 ..+8], it=0..7, gt=0..2.
    f16x8 wb[8][3];
    #pragma unroll
    for (int it = 0; it < 8; ++it)
        #pragma unroll
        for (int gt = 0; gt < 3; ++gt)
            wb[it][gt] = *(const f16x8*)(Whh16 + (size_t)(gt * DD + j0 + mfrag) * DD
                                         + kq * 256 + it * 32 + qk * 8);

    for (int i = tid; i < RG * 18; i += 256) ((float*)h32)[i] = 0.f;
    if (tid < 48) bh_s[tid >> 4][tid & 15] = bhh[(tid >> 4) * DD + j0 + (tid & 15)];
    __syncthreads();

    const int bg = (tid >> 3) & 7;    // combine: group-row 0..7 (tid<64 active)
    const int c2 = (tid & 7) * 2;     // combine: col pair 0..14
    const int act = tid < 64;

    // gi for t=0 (plain loads; drained by t=0's af vmcnt(0), one-time cost)
    unsigned giv_u[3], givn_u[3];
    if (act)
        #pragma unroll
        for (int gt = 0; gt < 3; ++gt)
            giv_u[gt] = *(const unsigned*)(GI + (size_t)(row0 + bg) * TT * G3D + gt * DD + j0 + c2);

    for (int t = 0; t < TT; ++t) {
        const int par = t & 1;
        const u64 slotR = (u64)hX + (u64)(par * 4 + g) * HSLOT_BYTES;

        // A-fragments of this group's 8 h rows; A-rows 8..15 alias rows 0..7
        // (same address -> coalesced, no extra line traffic). Per it the wave
        // covers a dense 512B region -> full 64B lines.
        f16x8 af[8];
        #pragma unroll
        for (int it = 0; it < 8; ++it) {
            u64 addr = slotR + (u64)((((kq * 8 + it) * 8 + (mfrag & 7)) << 6) + (qk << 4));
            asm volatile("global_load_dwordx4 %0, %1, off sc0 sc1"
                         : "=v"(af[it]) : "v"(addr) : "memory");
        }
        asm volatile("s_waitcnt vmcnt(0)" ::: "memory");
        __builtin_amdgcn_sched_barrier(0);

        // MFMA: B-frags straight from registers; no LDS in this phase.
        f32x4 acc[3] = {};
        #pragma unroll
        for (int it = 0; it < 8; ++it)
            #pragma unroll
            for (int gt = 0; gt < 3; ++gt)
                acc[gt] = __builtin_amdgcn_mfma_f32_16x16x32_f16(
                    af[it], wb[it][gt], acc[gt], 0, 0, 0);

        // dump K-partials; rows 8..15 (qk>=2) are duplicates -> skip.
        // C/D: col=lane&15, row=(lane>>4)*4+reg
        if (qk < 2)
            #pragma unroll
            for (int gt = 0; gt < 3; ++gt)
                #pragma unroll
                for (int r = 0; r < 4; ++r)
                    red[kq][gt][qk * 4 + r][mfrag] = acc[gt][r];
        // LDS-visibility barrier only (no vmcnt drain)
        asm volatile("s_waitcnt lgkmcnt(0)\n\ts_barrier" ::: "memory");

        // combine: thread (tid<64) -> group-row bg, cols {c2, c2+1}
        if (act) {
            float2 gr = make_float2(0.f, 0.f), gz = gr, gn = gr;
            #pragma unroll
            for (int q = 0; q < 4; ++q) {
                float2 vr = *(const float2*)&red[q][0][bg][c2];
                float2 vz = *(const float2*)&red[q][1][bg][c2];
                float2 vn = *(const float2*)&red[q][2][bg][c2];
                gr.x += vr.x; gr.y += vr.y;
                gz.x += vz.x; gz.y += vz.y;
                gn.x += vn.x; gn.y += vn.y;
            }
            union { unsigned u; f16x2 h; } gv[3];
            gv[0].u = giv_u[0]; gv[1].u = giv_u[1]; gv[2].u = giv_u[2];
            float hnew[2];
            #pragma unroll
            for (int cc = 0; cc < 2; ++cc) {
                float ghr = cc ? gr.y : gr.x;
                float ghz = cc ? gz.y : gz.x;
                float ghn = cc ? gn.y : gn.x;
                float pr = (float)gv[0].h[cc] + ghr + bh_s[0][c2 + cc];
                float pz = (float)gv[1].h[cc] + ghz + bh_s[1][c2 + cc];
                float r  = 1.f / (1.f + __expf(-pr));
                float z  = 1.f / (1.f + __expf(-pz));
                float pn = (float)gv[2].h[cc] + r * (ghn + bh_s[2][c2 + cc]);
                float e  = __expf(-2.f * fabsf(pn));
                float tn = (1.f - e) / (1.f + e);
                tn = pn < 0.f ? -tn : tn;
                float hold = h32[bg][c2 + cc];
                float hn2 = tn + z * (hold - tn);
                h32[bg][c2 + cc] = hn2;
                hnew[cc] = hn2;
            }
            // ---- asm-pinned VMEM sequence: [publish][gi x3][out] then
            // vmcnt(4): waits ONLY the publish (in-order retirement, m135).
            union { unsigned u; f16x2 h; } pk;
            pk.h[0] = (f16)hnew[0]; pk.h[1] = (f16)hnew[1];
            int col = j0 + c2;
            unsigned hidx = ((unsigned)(col >> 5) * 8 + (unsigned)bg) * 16
                          + (unsigned)((col & 31) >> 1);
            unsigned int* hp = (unsigned int*)hX
                             + (size_t)((par ^ 1) * 4 + g) * (HSLOT_BYTES / 4);
            __hip_atomic_store(hp + hidx, pk.u, __ATOMIC_RELAXED, __HIP_MEMORY_SCOPE_AGENT);
            asm volatile("" ::: "memory");   // pin: nothing crosses the publish
            {
                int tn2 = (t + 1 < TT) ? t + 1 : t;
                const f16* gib = GI + ((size_t)(row0 + bg) * TT + tn2) * G3D + j0 + c2;
                #pragma unroll
                for (int gt = 0; gt < 3; ++gt) {
                    u64 ga = (u64)(gib + gt * DD);
                    asm volatile("global_load_dword %0, %1, off"
                                 : "=v"(givn_u[gt]) : "v"(ga) : "memory");
                }
                f32x2 ov; ov.x = hnew[0]; ov.y = hnew[1];
                u64 oa = (u64)(out + ((size_t)(row0 + bg) * TT + t) * DD + j0 + c2);
                asm volatile("global_store_dwordx2 %0, %1, off"
                             :: "v"(oa), "v"(ov) : "memory");
            }
        }
        asm volatile("s_waitcnt vmcnt(4)" ::: "memory");  // publish acked; gi/out in flight
        asm volatile("s_barrier" ::: "memory");           // all waves' publishes acked

        // per-group parallel flag fan-in/out (64 col-blocks of group g)
        if (tid == 0)
            __hip_atomic_store(flags + bid * 16, (unsigned)(t + 1),
                               __ATOMIC_RELAXED, __HIP_MEMORY_SCOPE_AGENT);
        if (tid < 64) {
            while (__hip_atomic_load(flags + (tid * 4 + g) * 16, __ATOMIC_RELAXED,
                                     __HIP_MEMORY_SCOPE_AGENT) < (unsigned)(t + 1))
                __builtin_amdgcn_s_sleep(1);
        }
        asm volatile("s_barrier" ::: "memory");

        if (act) { giv_u[0] = givn_u[0]; giv_u[1] = givn_u[1]; giv_u[2] = givn_u[2]; }
    }
}

// ---------------------------------------------------------------- launch
extern "C" void kernel_launch(void* const* d_in, const int* in_sizes, int n_in,
                              void* d_out, int out_size, void* d_ws, size_t ws_size,
                              hipStream_t stream) {
    const float* h_enc = (const float*)d_in[0];
    const float* Wih   = (const float*)d_in[1];
    const float* Whh   = (const float*)d_in[2];
    const float* bih   = (const float*)d_in[3];
    const float* bhh   = (const float*)d_in[4];
    float* out = (float*)d_out;

    char* ws = (char*)d_ws;
    // ws layout: GI 100663296 | Wih16 6291456 | Whh16 6291456 | hX 131072 | flags 16384
    f16* GI     = (f16*)(ws);
    f16* Wih16  = (f16*)(ws + 100663296);
    f16* Whh16  = (f16*)(ws + 106954752);
    f16* hX     = (f16*)(ws + 113246208);
    unsigned int* flags = (unsigned int*)(ws + 113377280);

    hipLaunchKernelGGL(k_convert, dim3(12288), dim3(256), 0, stream,
                       Wih, Whh, Wih16, Whh16, (u64*)hX, flags);
    hipLaunchKernelGGL(k_pregemm, dim3(24, 128), dim3(256), 0, stream,
                       h_enc, Wih16, bih, GI);
    hipLaunchKernelGGL(k_gru, dim3(NBLK), dim3(256), 0, stream,
                       Whh16, GI, bhh, out, hX, flags);
}